// Round 6
// baseline (1305.184 us; speedup 1.0000x reference)
//
#include <hip/hip_runtime.h>
#include <stdint.h>
#include <stddef.h>

#define NROWS 8192
#define NCOLS 8192       // K dimension = noise-matrix column count
#define DDIM  1024
#define NCHUNK 64        // 128 rows per chunk
#define PROD_BLOCKS 512
#define CONS_BLOCKS 256

typedef float  f32x4 __attribute__((ext_vector_type(4)));
typedef _Float16 f16x8 __attribute__((ext_vector_type(8)));

#if __has_builtin(__builtin_amdgcn_exp2f)
#define EXP2F(x) __builtin_amdgcn_exp2f(x)
#else
#define EXP2F(x) exp2f(x)
#endif
#if __has_builtin(__builtin_amdgcn_logf)
#define LOG2F(x) __builtin_amdgcn_logf(x)     // v_log_f32 = log2
#else
#define LOG2F(x) log2f(x)
#endif
#if __has_builtin(__builtin_amdgcn_sqrtf)
#define SQRTF(x) __builtin_amdgcn_sqrtf(x)
#else
#define SQRTF(x) sqrtf(x)
#endif

// ---------------- Threefry-2x32, key = (0, 42) (jax.random.key(42)) ---------
__device__ __forceinline__ uint32_t rotl32(uint32_t x, uint32_t r){
  return (x << r) | (x >> (32u - r));
}

__device__ __forceinline__ void threefry2x32(uint32_t x0, uint32_t x1,
                                             uint32_t& o0, uint32_t& o1){
  const uint32_t k0 = 0u, k1 = 42u;
  const uint32_t k2 = k0 ^ k1 ^ 0x1BD11BDAu;
  x0 += k0; x1 += k1;
#define TF_R(r) { x0 += x1; x1 = rotl32(x1, r); x1 ^= x0; }
  TF_R(13) TF_R(15) TF_R(26) TF_R(6)
  x0 += k1; x1 += k2 + 1u;
  TF_R(17) TF_R(29) TF_R(16) TF_R(24)
  x0 += k2; x1 += k0 + 2u;
  TF_R(13) TF_R(15) TF_R(26) TF_R(6)
  x0 += k0; x1 += k1 + 3u;
  TF_R(17) TF_R(29) TF_R(16) TF_R(24)
  x0 += k1; x1 += k2 + 4u;
  TF_R(13) TF_R(15) TF_R(26) TF_R(6)
  x0 += k2; x1 += k0 + 5u;
#undef TF_R
  o0 = x0; o1 = x1;
}

// Partitionable-threefry element: flat index f -> E' = exp(2*normal)*2^-4.
__device__ __forceinline__ float elemE(uint32_t f){
  uint32_t o0, o1;
  threefry2x32(0u, f, o0, o1);
  const uint32_t b = o0 ^ o1;
  float u = __uint_as_float((b >> 9) | 0x3F800000u) - 1.0f;   // [0,1)
  const float lo = -0.99999994f;                              // nextafter(-1,0)
  float v = fmaf(u, 2.0f, lo);
  v = fmaxf(v, lo);
  const float t1 = fmaf(-v, v, 1.0f);                         // 1 - v^2
  float w = LOG2F(t1) * (-0.69314718f);                       // -ln(1-v^2)
  float p;
  if (w < 5.0f){
    w -= 2.5f;
    p =              3.97426473e-08f;
    p = fmaf(p, w,   4.85465e-07f);
    p = fmaf(p, w,  -4.98283e-06f);
    p = fmaf(p, w,  -6.21053e-06f);
    p = fmaf(p, w,   3.09120e-04f);
    p = fmaf(p, w,  -1.77290e-03f);
    p = fmaf(p, w,  -5.90817e-03f);
    p = fmaf(p, w,   3.48803163e-01f);
    p = fmaf(p, w,   2.12331355e+00f);
  } else {
    w = SQRTF(w) - 3.0f;
    p =             -2.83147363e-04f;
    p = fmaf(p, w,   1.42765560e-04f);
    p = fmaf(p, w,   1.90825981e-03f);
    p = fmaf(p, w,  -5.19500608e-03f);
    p = fmaf(p, w,   8.11688602e-03f);
    p = fmaf(p, w,  -1.07798386e-02f);
    p = fmaf(p, w,   1.33487061e-02f);
    p = fmaf(p, w,   1.41658096e+00f);
    p = fmaf(p, w,   4.00643396e+00f);
  }
  const float m = p * v;                         // sqrt(2)*erfinv(v) ~ N(0,1)
  return EXP2F(fmaf(m, 2.8853900817779268f, -4.0f)); // exp(2m)*2^-4
}

__device__ __forceinline__ uint16_t f2h(float a){
  union { _Float16 h; uint16_t u; } c; c.h = (_Float16)a; return c.u;
}

// ---------------- x [8192][1024] f32 -> xT [1024][8192] f16 -----------------
__global__ __launch_bounds__(256) void transpose_cast(const float* __restrict__ x,
                                                      uint16_t* __restrict__ xT){
  __shared__ float tile[32][33];
  const int tx = threadIdx.x & 31;
  const int ty = threadIdx.x >> 5;          // 0..7
  const int dcol = blockIdx.x * 32;
  const int nrow = blockIdx.y * 32;
  #pragma unroll
  for (int r = 0; r < 32; r += 8)
    tile[ty + r][tx] = x[(size_t)(nrow + ty + r) * DDIM + dcol + tx];
  __syncthreads();
  #pragma unroll
  for (int r = 0; r < 32; r += 8)
    xT[(size_t)(dcol + ty + r) * NROWS + nrow + tx] = f2h(tile[tx][ty + r]);
}

// ---------------- GEMM geometry --------------------------------------------
#define BM 128
#define BN 128
#define BK 32

typedef const __attribute__((address_space(1))) void GAS;
typedef __attribute__((address_space(3))) void LAS;

__device__ __forceinline__ void gload16(const void* g, void* l){
  __builtin_amdgcn_global_load_lds((GAS*)g, (LAS*)l, 16, 0, 0);
}

// ================== FUSED producer-consumer kernel ==========================
// grid = 768 blocks @ 3 blocks/CU co-resident.
// blocks [0,512)   : producers. Block b owns row rsub=b>>2 of every chunk,
//                    col-strip q=b&3 (2048 cols). Publishes cnt[2c + (q>>1)]
//                    with an agent-RELEASE fetch_add (built-in wbl2 flushes
//                    P stores to the coherent point). No other fences.
// blocks [512,768) : consumers. Block i handles tiles (chunk=i>>3, n=i&7) and
//                    (chunk=32+(i>>3), n=i&7), in that order. Thread 0 polls
//                    with RELAXED agent fetch_add(+0) (coherent-point read, NO
//                    cache invalidation), then ONE acquire fence per wait.
__global__ __launch_bounds__(256, 3) void fused_gen_gemm(
    uint16_t* __restrict__ P,           // [8192][8192] f16 (unnormalized E')
    const uint16_t* __restrict__ xT,    // [1024][8192] f16
    float* __restrict__ S,              // [8192] row sums (pre-zeroed)
    uint32_t* __restrict__ cnt,         // [128] ready counters (pre-zeroed)
    float* __restrict__ O)              // [8192][1024] f32
{
  __shared__ uint16_t smem[8192];       // consumers: As[128][32] | Bs[128][32]
  __shared__ float sm[4];               // producers: reduction scratch
  const int b = blockIdx.x;
  const int t = threadIdx.x;

  if (b < PROD_BLOCKS){
    // ------------------------------ producer ------------------------------
    const int rsub = b >> 2;            // row within chunk (0..127)
    const int q    = b & 3;             // 2048-col strip (0..3)
    const int h    = q >> 1;            // column half this block belongs to
    for (int c = 0; c < NCHUNK; ++c){
      const int row = c * 128 + rsub;
      const uint32_t j0 = (uint32_t)q * 2048u + ((uint32_t)t << 3);
      const uint32_t f0 = (uint32_t)row * 8192u + j0;
      float e[8];
      float part = 0.f;
      #pragma unroll
      for (int i = 0; i < 8; ++i){
        e[i] = elemE(f0 + (uint32_t)i);
        part += e[i];
      }
      f16x8 pk;
      #pragma unroll
      for (int i = 0; i < 8; ++i) pk[i] = (_Float16)e[i];
      *reinterpret_cast<f16x8*>(P + (size_t)row * NCOLS + j0) = pk;  // 16B store
      // block-reduce part -> S[row]; then publish
      float v = part;
      #pragma unroll
      for (int off = 32; off > 0; off >>= 1) v += __shfl_down(v, off, 64);
      __syncthreads();                  // prev sm read done; P stores drained
      if ((t & 63) == 0) sm[t >> 6] = v;
      __syncthreads();
      if (t == 0){
        atomicAdd(&S[row], (sm[0] + sm[1]) + (sm[2] + sm[3]));
        __hip_atomic_fetch_add(&cnt[2*c + h], 1u, __ATOMIC_RELEASE,
                               __HIP_MEMORY_SCOPE_AGENT);
      }
    }
  } else {
    // ------------------------------ consumer ------------------------------
    const int ci = b - PROD_BLOCKS;     // 0..255
    const int nq = ci & 7;
    const int cb = ci >> 3;             // 0..31
    const size_t n0 = (size_t)nq * BN;

    uint16_t* As = smem;
    uint16_t* Bs = smem + 4096;
    const int lane = t & 63;
    const int wave = t >> 6;
    const int wr = (wave >> 1) * 64;
    const int wc = (wave & 1) * 64;
    const int l15 = lane & 15;
    const int lq  = lane >> 4;

    const int lin0 = t, lin1 = t + 256;
    const int r0s = lin0 >> 2, k0s = (lin0 & 3) << 3;
    const int r1s = lin1 >> 2, k1s = (lin1 & 3) << 3;

    const uint16_t* gB0 = xT + (n0 + r0s) * (size_t)NCOLS + k0s;
    const uint16_t* gB1 = xT + (n0 + r1s) * (size_t)NCOLS + k1s;

    #pragma unroll 1
    for (int phase = 0; phase < 2; ++phase){
      const int cidx = cb + phase * 32;       // chunk / m-tile
      const size_t m0 = (size_t)cidx * BM;
      const uint16_t* gA0 = P + (m0 + r0s) * (size_t)NCOLS + k0s;
      const uint16_t* gA1 = P + (m0 + r1s) * (size_t)NCOLS + k1s;

      f32x4 acc[4][4];
      #pragma unroll
      for (int i = 0; i < 4; ++i)
        #pragma unroll
        for (int j = 0; j < 4; ++j)
          #pragma unroll
          for (int qq = 0; qq < 4; ++qq) acc[i][j][qq] = 0.0f;

      #pragma unroll 1
      for (int half = 0; half < 2; ++half){
        if (t == 0){
          // RELAXED RMW poll: reads at the coherent point, no cache inval.
          while (__hip_atomic_fetch_add(&cnt[2*cidx + half], 0u,
                                        __ATOMIC_RELAXED,
                                        __HIP_MEMORY_SCOPE_AGENT)
                 < (uint32_t)PROD_BLOCKS / 2)
            __builtin_amdgcn_s_sleep(32);
          __builtin_amdgcn_fence(__ATOMIC_ACQUIRE, "agent");  // one inv
        }
        __syncthreads();
        const int kend = (half + 1) * 4096;
        for (int k0 = half * 4096; k0 < kend; k0 += BK){
          gload16(gA0 + k0, As + lin0 * 8);
          gload16(gA1 + k0, As + lin1 * 8);
          gload16(gB0 + k0, Bs + lin0 * 8);
          gload16(gB1 + k0, Bs + lin1 * 8);
          __syncthreads();
          f16x8 af[4], bfrag[4];
          #pragma unroll
          for (int i = 0; i < 4; ++i)
            af[i] = *reinterpret_cast<const f16x8*>(As + (wr + i*16 + l15) * BK + lq * 8);
          #pragma unroll
          for (int j = 0; j < 4; ++j)
            bfrag[j] = *reinterpret_cast<const f16x8*>(Bs + (wc + j*16 + l15) * BK + lq * 8);
          #pragma unroll
          for (int i = 0; i < 4; ++i)
            #pragma unroll
            for (int j = 0; j < 4; ++j)
              acc[i][j] = __builtin_amdgcn_mfma_f32_16x16x32_f16(af[i], bfrag[j], acc[i][j], 0, 0, 0);
          __syncthreads();
        }
      }

      // epilogue: S complete & cache-fresh (half-1 acquire fence above)
      #pragma unroll
      for (int i = 0; i < 4; ++i){
        float rinv[4];
        #pragma unroll
        for (int r = 0; r < 4; ++r)
          rinv[r] = 1.0f / S[m0 + wr + i*16 + lq*4 + r];
        #pragma unroll
        for (int j = 0; j < 4; ++j){
          const size_t col = n0 + wc + j*16 + l15;
          #pragma unroll
          for (int r = 0; r < 4; ++r){
            const size_t row = m0 + wr + i*16 + lq*4 + r;  // C/D: col=lane&15, row=quad*4+reg
            O[row * DDIM + col] = acc[i][j][r] * rinv[r];
          }
        }
      }
    }
  }
}

// ================== Fallback (small workspace): unfused =====================
__global__ __launch_bounds__(256) void gen_rows(uint16_t* __restrict__ P,
                                                float* __restrict__ S, int row0){
  const int gi = row0 + blockIdx.x;
  const uint32_t base = (uint32_t)gi * 8192u;
  const int t = threadIdx.x;
  uint16_t* __restrict__ prow = P + (size_t)blockIdx.x * NCOLS;
  float acc = 0.0f;
  #pragma unroll
  for (int g = 0; g < 4; ++g){
    const uint32_t j0 = (uint32_t)(g * 2048) + ((uint32_t)t << 3);
    float e[8];
    #pragma unroll
    for (int i = 0; i < 8; ++i){ e[i] = elemE(base + j0 + (uint32_t)i); acc += e[i]; }
    f16x8 pk;
    #pragma unroll
    for (int i = 0; i < 8; ++i) pk[i] = (_Float16)e[i];
    *reinterpret_cast<f16x8*>(prow + j0) = pk;
  }
  #pragma unroll
  for (int off = 32; off > 0; off >>= 1) acc += __shfl_down(acc, off, 64);
  __shared__ float sm[4];
  if ((t & 63) == 0) sm[t >> 6] = acc;
  __syncthreads();
  if (t == 0) S[gi] = (sm[0] + sm[1]) + (sm[2] + sm[3]);
}

__global__ __launch_bounds__(256, 2) void gemm_rows(
    const uint16_t* __restrict__ P, const uint16_t* __restrict__ xT,
    const float* __restrict__ S, int row0, float* __restrict__ O)
{
  __shared__ uint16_t smem[8192];
  uint16_t* As = smem;
  uint16_t* Bs = smem + 4096;
  const int tid = threadIdx.x;
  const int lane = tid & 63;
  const int wave = tid >> 6;
  const int wr = (wave >> 1) * 64;
  const int wc = (wave & 1) * 64;
  const int l15 = lane & 15;
  const int lq  = lane >> 4;
  const size_t m0 = (size_t)blockIdx.x * BM;
  const size_t n0 = (size_t)blockIdx.y * BN;
  const int lin0 = tid, lin1 = tid + 256;
  const int r0s = lin0 >> 2, k0s = (lin0 & 3) << 3;
  const int r1s = lin1 >> 2, k1s = (lin1 & 3) << 3;
  const uint16_t* gA0 = P  + (m0 + r0s) * (size_t)NCOLS + k0s;
  const uint16_t* gA1 = P  + (m0 + r1s) * (size_t)NCOLS + k1s;
  const uint16_t* gB0 = xT + (n0 + r0s) * (size_t)NCOLS + k0s;
  const uint16_t* gB1 = xT + (n0 + r1s) * (size_t)NCOLS + k1s;
  f32x4 acc[4][4];
  #pragma unroll
  for (int i = 0; i < 4; ++i)
    #pragma unroll
    for (int j = 0; j < 4; ++j)
      #pragma unroll
      for (int q = 0; q < 4; ++q) acc[i][j][q] = 0.0f;
  for (int k0 = 0; k0 < NCOLS; k0 += BK){
    gload16(gA0 + k0, As + lin0 * 8);
    gload16(gA1 + k0, As + lin1 * 8);
    gload16(gB0 + k0, Bs + lin0 * 8);
    gload16(gB1 + k0, Bs + lin1 * 8);
    __syncthreads();
    f16x8 af[4], bfrag[4];
    #pragma unroll
    for (int i = 0; i < 4; ++i)
      af[i] = *reinterpret_cast<const f16x8*>(As + (wr + i*16 + l15) * BK + lq * 8);
    #pragma unroll
    for (int j = 0; j < 4; ++j)
      bfrag[j] = *reinterpret_cast<const f16x8*>(Bs + (wc + j*16 + l15) * BK + lq * 8);
    #pragma unroll
    for (int i = 0; i < 4; ++i)
      #pragma unroll
      for (int j = 0; j < 4; ++j)
        acc[i][j] = __builtin_amdgcn_mfma_f32_16x16x32_f16(af[i], bfrag[j], acc[i][j], 0, 0, 0);
    __syncthreads();
  }
  #pragma unroll
  for (int i = 0; i < 4; ++i){
    float rinv[4];
    #pragma unroll
    for (int r = 0; r < 4; ++r)
      rinv[r] = 1.0f / S[row0 + m0 + wr + i*16 + lq*4 + r];
    #pragma unroll
    for (int j = 0; j < 4; ++j){
      const size_t col = n0 + wc + j*16 + l15;
      #pragma unroll
      for (int r = 0; r < 4; ++r){
        const size_t row = m0 + wr + i*16 + lq*4 + r;
        O[row * DDIM + col] = acc[i][j][r] * rinv[r];
      }
    }
  }
}

// ---------------------------------------------------------------------------
extern "C" void kernel_launch(void* const* d_in, const int* in_sizes, int n_in,
                              void* d_out, int out_size, void* d_ws, size_t ws_size,
                              hipStream_t stream)
{
  (void)in_sizes; (void)n_in; (void)out_size;
  const float* x = (const float*)d_in[0];       // [8192][1024] f32; d_in[1] unused
  float* O = (float*)d_out;                     // [8192][1024] f32
  uint8_t* ws = (uint8_t*)d_ws;

  // layout: cnt[128] u32 | S[8192] f32 | xT (16.8 MB) | P (134 MB)
  uint32_t* cnt = (uint32_t*)ws;
  const size_t cnt_bytes = 128 * sizeof(uint32_t);
  float* S = (float*)(ws + cnt_bytes);
  const size_t S_bytes = (size_t)NROWS * sizeof(float);
  uint16_t* xT = (uint16_t*)(ws + cnt_bytes + S_bytes);
  const size_t xT_bytes = (size_t)DDIM * NROWS * sizeof(uint16_t);
  uint16_t* P = (uint16_t*)(ws + cnt_bytes + S_bytes + xT_bytes);
  const size_t used = cnt_bytes + S_bytes + xT_bytes;
  const size_t avail = ws_size > used ? ws_size - used : 0;

  hipMemsetAsync(ws, 0, cnt_bytes + S_bytes, stream);   // zero cnt + S
  transpose_cast<<<dim3(DDIM/32, NROWS/32), 256, 0, stream>>>(x, xT);

  const size_t fullP = (size_t)NROWS * NCOLS * sizeof(uint16_t); // 134 MB
  if (avail >= fullP){
    fused_gen_gemm<<<PROD_BLOCKS + CONS_BLOCKS, 256, 0, stream>>>(P, xT, S, cnt, O);
  } else {
    int R = 128;
    for (int r = 4096; r >= 128; r >>= 1)
      if ((size_t)r * NCOLS * sizeof(uint16_t) <= avail){ R = r; break; }
    for (int r0 = 0; r0 < NROWS; r0 += R){
      gen_rows<<<R, 256, 0, stream>>>(P, S, r0);
      gemm_rows<<<dim3(R/BM, DDIM/BN), 256, 0, stream>>>(P, xT, S, r0, O + (size_t)r0 * DDIM);
    }
  }
}

// Round 7
// 327.674 us; speedup vs baseline: 3.9832x; 3.9832x over previous
//
#include <hip/hip_runtime.h>
#include <stdint.h>
#include <stddef.h>

#define NROWS 8192
#define NCOLS 8192       // K dimension = noise-matrix column count
#define DDIM  1024

typedef float  f32x4 __attribute__((ext_vector_type(4)));
typedef _Float16 f16x8 __attribute__((ext_vector_type(8)));

#if __has_builtin(__builtin_amdgcn_exp2f)
#define EXP2F(x) __builtin_amdgcn_exp2f(x)
#else
#define EXP2F(x) exp2f(x)
#endif
#if __has_builtin(__builtin_amdgcn_logf)
#define LOG2F(x) __builtin_amdgcn_logf(x)     // v_log_f32 = log2
#else
#define LOG2F(x) log2f(x)
#endif
#if __has_builtin(__builtin_amdgcn_sqrtf)
#define SQRTF(x) __builtin_amdgcn_sqrtf(x)
#else
#define SQRTF(x) sqrtf(x)
#endif

// ---------------- Threefry-2x32, key = (0, 42) (jax.random.key(42)) ---------
__device__ __forceinline__ uint32_t rotl32(uint32_t x, uint32_t r){
  return (x << r) | (x >> (32u - r));
}

__device__ __forceinline__ void threefry2x32(uint32_t x0, uint32_t x1,
                                             uint32_t& o0, uint32_t& o1){
  const uint32_t k0 = 0u, k1 = 42u;
  const uint32_t k2 = k0 ^ k1 ^ 0x1BD11BDAu;
  x0 += k0; x1 += k1;
#define TF_R(r) { x0 += x1; x1 = rotl32(x1, r); x1 ^= x0; }
  TF_R(13) TF_R(15) TF_R(26) TF_R(6)
  x0 += k1; x1 += k2 + 1u;
  TF_R(17) TF_R(29) TF_R(16) TF_R(24)
  x0 += k2; x1 += k0 + 2u;
  TF_R(13) TF_R(15) TF_R(26) TF_R(6)
  x0 += k0; x1 += k1 + 3u;
  TF_R(17) TF_R(29) TF_R(16) TF_R(24)
  x0 += k1; x1 += k2 + 4u;
  TF_R(13) TF_R(15) TF_R(26) TF_R(6)
  x0 += k2; x1 += k0 + 5u;
#undef TF_R
  o0 = x0; o1 = x1;
}

// Partitionable-threefry element: flat index f -> E' = exp(2*normal)*2^-4.
__device__ __forceinline__ float elemE(uint32_t f){
  uint32_t o0, o1;
  threefry2x32(0u, f, o0, o1);
  const uint32_t b = o0 ^ o1;
  float u = __uint_as_float((b >> 9) | 0x3F800000u) - 1.0f;   // [0,1)
  const float lo = -0.99999994f;                              // nextafter(-1,0)
  float v = fmaf(u, 2.0f, lo);
  v = fmaxf(v, lo);
  const float t1 = fmaf(-v, v, 1.0f);                         // 1 - v^2
  float w = LOG2F(t1) * (-0.69314718f);                       // -ln(1-v^2)
  float p;
  if (w < 5.0f){
    w -= 2.5f;
    p =              3.97426473e-08f;
    p = fmaf(p, w,   4.85465e-07f);
    p = fmaf(p, w,  -4.98283e-06f);
    p = fmaf(p, w,  -6.21053e-06f);
    p = fmaf(p, w,   3.09120e-04f);
    p = fmaf(p, w,  -1.77290e-03f);
    p = fmaf(p, w,  -5.90817e-03f);
    p = fmaf(p, w,   3.48803163e-01f);
    p = fmaf(p, w,   2.12331355e+00f);
  } else {
    w = SQRTF(w) - 3.0f;
    p =             -2.83147363e-04f;
    p = fmaf(p, w,   1.42765560e-04f);
    p = fmaf(p, w,   1.90825981e-03f);
    p = fmaf(p, w,  -5.19500608e-03f);
    p = fmaf(p, w,   8.11688602e-03f);
    p = fmaf(p, w,  -1.07798386e-02f);
    p = fmaf(p, w,   1.33487061e-02f);
    p = fmaf(p, w,   1.41658096e+00f);
    p = fmaf(p, w,   4.00643396e+00f);
  }
  const float m = p * v;                         // sqrt(2)*erfinv(v) ~ N(0,1)
  return EXP2F(fmaf(m, 2.8853900817779268f, -4.0f)); // exp(2m)*2^-4
}

__device__ __forceinline__ uint16_t f2h(float a){
  union { _Float16 h; uint16_t u; } c; c.h = (_Float16)a; return c.u;
}

// ---------------- fallback transpose: x [8192][1024] f32 -> xT f16 ----------
__global__ __launch_bounds__(256) void transpose_cast(const float* __restrict__ x,
                                                      uint16_t* __restrict__ xT){
  __shared__ float tile[32][33];
  const int tx = threadIdx.x & 31;
  const int ty = threadIdx.x >> 5;          // 0..7
  const int dcol = blockIdx.x * 32;
  const int nrow = blockIdx.y * 32;
  #pragma unroll
  for (int r = 0; r < 32; r += 8)
    tile[ty + r][tx] = x[(size_t)(nrow + ty + r) * DDIM + dcol + tx];
  __syncthreads();
  #pragma unroll
  for (int r = 0; r < 32; r += 8)
    xT[(size_t)(dcol + ty + r) * NROWS + nrow + tx] = f2h(tile[tx][ty + r]);
}

// ---------------- full path: transpose tile + gen row, one dispatch ---------
// Block b (0..8191): (1) transposes 32x32 tile (dcol=(b&31)*32, nrow=(b>>5)*32)
// of x into xT; (2) generates P row b (E' = exp(2m)*2^-4, fp16) + row sum S[b].
__global__ __launch_bounds__(256) void gen_trans_rows(const float* __restrict__ x,
                                                      uint16_t* __restrict__ xT,
                                                      uint16_t* __restrict__ P,
                                                      float* __restrict__ S){
  const int t = threadIdx.x;
  // ---- transpose part ----
  {
    __shared__ float tile[32][33];
    const int tx = t & 31;
    const int ty = t >> 5;                  // 0..7
    const int dcol = (blockIdx.x & 31) * 32;
    const int nrow = (blockIdx.x >> 5) * 32;
    #pragma unroll
    for (int r = 0; r < 32; r += 8)
      tile[ty + r][tx] = x[(size_t)(nrow + ty + r) * DDIM + dcol + tx];
    __syncthreads();
    #pragma unroll
    for (int r = 0; r < 32; r += 8)
      xT[(size_t)(dcol + ty + r) * NROWS + nrow + tx] = f2h(tile[tx][ty + r]);
  }
  // ---- gen part ----
  const int gi = blockIdx.x;
  const uint32_t base = (uint32_t)gi * 8192u;
  uint16_t* __restrict__ prow = P + (size_t)gi * NCOLS;
  float acc = 0.0f;
  #pragma unroll
  for (int g = 0; g < 4; ++g){
    const uint32_t j0 = (uint32_t)(g * 2048) + ((uint32_t)t << 3);
    float e[8];
    #pragma unroll
    for (int i = 0; i < 8; ++i){ e[i] = elemE(base + j0 + (uint32_t)i); acc += e[i]; }
    f16x8 pk;
    #pragma unroll
    for (int i = 0; i < 8; ++i) pk[i] = (_Float16)e[i];
    *reinterpret_cast<f16x8*>(prow + j0) = pk;    // 16B coalesced store
  }
  #pragma unroll
  for (int off = 32; off > 0; off >>= 1) acc += __shfl_down(acc, off, 64);
  __shared__ float sm[4];
  __syncthreads();
  if ((t & 63) == 0) sm[t >> 6] = acc;
  __syncthreads();
  if (t == 0) S[gi] = (sm[0] + sm[1]) + (sm[2] + sm[3]);
}

// ---------------- fallback gen (chunked workspace) --------------------------
__global__ __launch_bounds__(256) void gen_rows(uint16_t* __restrict__ P,
                                                float* __restrict__ S, int row0){
  const int gi = row0 + blockIdx.x;
  const uint32_t base = (uint32_t)gi * 8192u;
  const int t = threadIdx.x;
  uint16_t* __restrict__ prow = P + (size_t)blockIdx.x * NCOLS;
  float acc = 0.0f;
  #pragma unroll
  for (int g = 0; g < 4; ++g){
    const uint32_t j0 = (uint32_t)(g * 2048) + ((uint32_t)t << 3);
    float e[8];
    #pragma unroll
    for (int i = 0; i < 8; ++i){ e[i] = elemE(base + j0 + (uint32_t)i); acc += e[i]; }
    f16x8 pk;
    #pragma unroll
    for (int i = 0; i < 8; ++i) pk[i] = (_Float16)e[i];
    *reinterpret_cast<f16x8*>(prow + j0) = pk;
  }
  #pragma unroll
  for (int off = 32; off > 0; off >>= 1) acc += __shfl_down(acc, off, 64);
  __shared__ float sm[4];
  if ((t & 63) == 0) sm[t >> 6] = acc;
  __syncthreads();
  if (t == 0) S[gi] = (sm[0] + sm[1]) + (sm[2] + sm[3]);
}

// ---------------- GEMM: O[r][d] = (1/S[r]) * sum_k E'[r][k] * xT[d][k] ------
// BK=64 (half the barriers of BK=32), XOR-swizzled LDS (conflict-free
// ds_read_b128), 3 blocks/CU.
#define BM 128
#define BN 128
#define BK 64

typedef const __attribute__((address_space(1))) void GAS;
typedef __attribute__((address_space(3))) void LAS;

__device__ __forceinline__ void gload16(const void* g, void* l){
  __builtin_amdgcn_global_load_lds((GAS*)g, (LAS*)l, 16, 0, 0);
}

__global__ __launch_bounds__(256, 3) void gemm_rows(
    const uint16_t* __restrict__ P,     // [Rchunk][8192] f16 (unnormalized E')
    const uint16_t* __restrict__ xT,    // [1024][8192] f16
    const float* __restrict__ S,        // [8192] row sums (global rows)
    int row0,                           // global row of P's row 0
    float* __restrict__ O)              // [Rchunk][1024] f32
{
  __shared__ uint16_t smem[16384];      // As[128][64] | Bs[128][64]
  uint16_t* As = smem;
  uint16_t* Bs = smem + 8192;

  const int tid  = threadIdx.x;
  const int lane = tid & 63;
  const int wave = tid >> 6;
  const int wr = (wave >> 1) * 64;
  const int wc = (wave & 1) * 64;
  const int l15 = lane & 15;
  const int lq  = lane >> 4;

  const size_t m0 = (size_t)blockIdx.x * BM;
  const size_t n0 = (size_t)blockIdx.y * BN;

  // Staging map: LDS chunk lin (0..1023) = row (lin>>3), phys kc8 (lin&7).
  // Phys slot kc8 holds logical k-group kc8 ^ (row&7)  (XOR swizzle).
  // For thread t, repeats r=0..3: lin = t + 256r -> row = (t>>3)+32r,
  // kc8 = t&7, row&7 = (t>>3)&7 for all r.
  const int srow = tid >> 3;                    // 0..31
  const int sx   = (tid & 7) ^ (srow & 7);      // swizzled source k-group
  const uint16_t* gA = P  + (m0 + srow) * (size_t)NCOLS + sx * 8;
  const uint16_t* gB = xT + (n0 + srow) * (size_t)NCOLS + sx * 8;

  f32x4 acc[4][4];
  #pragma unroll
  for (int i = 0; i < 4; ++i)
    #pragma unroll
    for (int j = 0; j < 4; ++j)
      #pragma unroll
      for (int q = 0; q < 4; ++q) acc[i][j][q] = 0.0f;

  const int axor = l15 & 7;                     // frag-read swizzle term

  for (int k0 = 0; k0 < NCOLS; k0 += BK){
    #pragma unroll
    for (int r = 0; r < 4; ++r)
      gload16(gA + (size_t)(32 * r) * NCOLS + k0, As + (tid + 256 * r) * 8);
    #pragma unroll
    for (int r = 0; r < 4; ++r)
      gload16(gB + (size_t)(32 * r) * NCOLS + k0, Bs + (tid + 256 * r) * 8);
    __syncthreads();
    #pragma unroll
    for (int ks = 0; ks < 2; ++ks){
      const int kphys = ((lq + 4 * ks) ^ axor) * 8;
      f16x8 af[4], bfrag[4];
      #pragma unroll
      for (int i = 0; i < 4; ++i)
        af[i] = *reinterpret_cast<const f16x8*>(As + (wr + i*16 + l15) * BK + kphys);
      #pragma unroll
      for (int j = 0; j < 4; ++j)
        bfrag[j] = *reinterpret_cast<const f16x8*>(Bs + (wc + j*16 + l15) * BK + kphys);
      #pragma unroll
      for (int i = 0; i < 4; ++i)
        #pragma unroll
        for (int j = 0; j < 4; ++j)
          acc[i][j] = __builtin_amdgcn_mfma_f32_16x16x32_f16(af[i], bfrag[j], acc[i][j], 0, 0, 0);
    }
    __syncthreads();
  }

  #pragma unroll
  for (int i = 0; i < 4; ++i){
    float rinv[4];
    #pragma unroll
    for (int r = 0; r < 4; ++r)
      rinv[r] = 1.0f / S[row0 + m0 + wr + i*16 + lq*4 + r];
    #pragma unroll
    for (int j = 0; j < 4; ++j){
      const size_t col = n0 + wc + j*16 + l15;
      #pragma unroll
      for (int r = 0; r < 4; ++r){
        const size_t row = m0 + wr + i*16 + lq*4 + r;  // C/D: col=lane&15, row=quad*4+reg
        O[row * DDIM + col] = acc[i][j][r] * rinv[r];
      }
    }
  }
}

// ---------------------------------------------------------------------------
extern "C" void kernel_launch(void* const* d_in, const int* in_sizes, int n_in,
                              void* d_out, int out_size, void* d_ws, size_t ws_size,
                              hipStream_t stream)
{
  (void)in_sizes; (void)n_in; (void)out_size;
  const float* x = (const float*)d_in[0];       // [8192][1024] f32; d_in[1] unused
  float* O = (float*)d_out;                     // [8192][1024] f32
  uint8_t* ws = (uint8_t*)d_ws;

  // layout: S[8192] f32 | xT (16.8 MB) | P (134 MB)
  float* S = (float*)ws;
  const size_t S_bytes = (size_t)NROWS * sizeof(float);
  uint16_t* xT = (uint16_t*)(ws + S_bytes);
  const size_t xT_bytes = (size_t)DDIM * NROWS * sizeof(uint16_t);
  uint16_t* P = (uint16_t*)(ws + S_bytes + xT_bytes);
  const size_t used = S_bytes + xT_bytes;
  const size_t avail = ws_size > used ? ws_size - used : 0;

  const size_t fullP = (size_t)NROWS * NCOLS * sizeof(uint16_t); // 134 MB
  if (avail >= fullP){
    gen_trans_rows<<<NROWS, 256, 0, stream>>>(x, xT, P, S);
    gemm_rows<<<dim3(NROWS/BM, DDIM/BN), 256, 0, stream>>>(P, xT, S, 0, O);
  } else {
    transpose_cast<<<dim3(DDIM/32, NROWS/32), 256, 0, stream>>>(x, xT);
    int R = 128;
    for (int r = 4096; r >= 128; r >>= 1)
      if ((size_t)r * NCOLS * sizeof(uint16_t) <= avail){ R = r; break; }
    for (int r0 = 0; r0 < NROWS; r0 += R){
      gen_rows<<<R, 256, 0, stream>>>(P, S, r0);
      gemm_rows<<<dim3(R/BM, DDIM/BN), 256, 0, stream>>>(P, xT, S, r0, O + (size_t)r0 * DDIM);
    }
  }
}